// Round 9
// baseline (254.516 us; speedup 1.0000x reference)
//
#include <hip/hip_runtime.h>
#include <hip/hip_fp16.h>

#define IN_F 128
#define HID  128
#define NC   10
#define H2P  16     // h2 row stride in HALVES (32 B)
#define NPB  128    // nodes per bin (bin = dst>>7, local = dst&127)
#define NBMAX 784   // max bins (N=100000 -> 782)
#define BCAP 2560   // per-bin edge capacity (mean 2046, +11 sigma)
#define EPB2 4096   // edges per bin-block (256 thr x 16)
#define SWLD 136    // padded LDS stride (halves): 272 B, 16B-aligned

typedef _Float16 f16x8 __attribute__((ext_vector_type(8)));
typedef float f32x4 __attribute__((ext_vector_type(4)));

__device__ inline __half2 shfl_xor_h2(__half2 v, int mask) {
    int i = __shfl_xor(*reinterpret_cast<int*>(&v), mask, 64);
    return *reinterpret_cast<__half2*>(&i);
}

// ------- merged: bin blocks (0..nbinblk-1) + GEMM1 blocks (rest) -------------
// Bin: histogram edges by dst>>7 into per-bin regions, packed (dl<<17)|src.
// GEMM: hsh = fp16(X @ W1) UNSCALED (dis applied per-edge in agg1), so this
// half is independent of the bin half and they overlap on the machine.
__global__ __launch_bounds__(256) void k_bingemm(const int* __restrict__ src,
                                                 const int* __restrict__ dst,
                                                 int* __restrict__ bcnt,
                                                 unsigned int* __restrict__ binned,
                                                 const float* __restrict__ X,
                                                 const float* __restrict__ W1,
                                                 __half* __restrict__ hsh,
                                                 int E, int nbin, int nbinblk) {
    __shared__ __align__(16) char smem[43520];
    const int tid = threadIdx.x;

    if ((int)blockIdx.x < nbinblk) {
        // ---------------- binning ----------------
        int* hist = (int*)smem;
        int* base = hist + NBMAX;
        int* lcur = base + NBMAX;
        for (int b = tid; b < nbin; b += 256) { hist[b] = 0; lcur[b] = 0; }
        __syncthreads();

        const int e0 = blockIdx.x * EPB2 + tid;
        int d[16];
        #pragma unroll
        for (int u = 0; u < 16; u++) {
            int e = e0 + u * 256;
            d[u] = (e < E) ? dst[e] : -1;
            if (d[u] >= 0) atomicAdd(&hist[d[u] >> 7], 1);
        }
        __syncthreads();
        for (int b = tid; b < nbin; b += 256) {
            int h = hist[b];
            base[b] = h ? atomicAdd(&bcnt[b], h) : 0;
        }
        __syncthreads();
        #pragma unroll
        for (int u = 0; u < 16; u++) {
            int e = e0 + u * 256;
            if (e < E) {
                int dd = d[u];
                int b = dd >> 7;
                int s = src[e];
                int o = base[b] + atomicAdd(&lcur[b], 1);
                if (o < BCAP)
                    binned[(size_t)b * BCAP + o] = ((unsigned)(dd & 127) << 17) | (unsigned)s;
            }
        }
    } else {
        // ---------------- GEMM1 (MFMA fp16), 32 rows x 128 cols -------------
        _Float16* sX = (_Float16*)smem;             // 32  x SWLD
        _Float16* sW = (_Float16*)(smem + 8704);    // 128 x SWLD
        const int row0 = ((int)blockIdx.x - nbinblk) * 32;

        // stage W1 fp32->fp16 transposed: sW[n][k] = W1[k][n] (reads coalesced)
        for (int i = tid; i < IN_F * HID; i += 256) {
            int k = i >> 7, n = i & 127;
            sW[n * SWLD + k] = (_Float16)W1[i];
        }
        // stage X fp32->fp16
        {
            int r = tid >> 3;
            int k0 = (tid & 7) * 16;
            const float* sp = X + (size_t)(row0 + r) * IN_F + k0;
            float4 f0 = *(const float4*)(sp);
            float4 f1 = *(const float4*)(sp + 4);
            float4 f2 = *(const float4*)(sp + 8);
            float4 f3 = *(const float4*)(sp + 12);
            f16x8 h0, h1;
            h0[0] = (_Float16)f0.x; h0[1] = (_Float16)f0.y;
            h0[2] = (_Float16)f0.z; h0[3] = (_Float16)f0.w;
            h0[4] = (_Float16)f1.x; h0[5] = (_Float16)f1.y;
            h0[6] = (_Float16)f1.z; h0[7] = (_Float16)f1.w;
            h1[0] = (_Float16)f2.x; h1[1] = (_Float16)f2.y;
            h1[2] = (_Float16)f2.z; h1[3] = (_Float16)f2.w;
            h1[4] = (_Float16)f3.x; h1[5] = (_Float16)f3.y;
            h1[6] = (_Float16)f3.z; h1[7] = (_Float16)f3.w;
            *(f16x8*)(sX + r * SWLD + k0) = h0;
            *(f16x8*)(sX + r * SWLD + k0 + 8) = h1;
        }
        __syncthreads();

        const int wave = tid >> 6;
        const int lane = tid & 63;
        const int quad = lane >> 4;
        const int l16 = lane & 15;
        const int nbase = wave * 32;

        f32x4 acc00 = {0,0,0,0}, acc01 = {0,0,0,0}, acc10 = {0,0,0,0}, acc11 = {0,0,0,0};

        #pragma unroll
        for (int kc = 0; kc < 4; kc++) {
            const int koff = kc * 32 + quad * 8;
            f16x8 a0 = *(const f16x8*)(sX + l16 * SWLD + koff);
            f16x8 a1 = *(const f16x8*)(sX + (16 + l16) * SWLD + koff);
            f16x8 b0 = *(const f16x8*)(sW + (nbase + l16) * SWLD + koff);
            f16x8 b1 = *(const f16x8*)(sW + (nbase + 16 + l16) * SWLD + koff);
            acc00 = __builtin_amdgcn_mfma_f32_16x16x32_f16(a0, b0, acc00, 0, 0, 0);
            acc01 = __builtin_amdgcn_mfma_f32_16x16x32_f16(a0, b1, acc01, 0, 0, 0);
            acc10 = __builtin_amdgcn_mfma_f32_16x16x32_f16(a1, b0, acc10, 0, 0, 0);
            acc11 = __builtin_amdgcn_mfma_f32_16x16x32_f16(a1, b1, acc11, 0, 0, 0);
        }

        #pragma unroll
        for (int r = 0; r < 4; r++) {
            {
                int row = row0 + quad * 4 + r;
                __half* o = hsh + (size_t)row * HID + nbase + l16;
                o[0]  = __float2half(acc00[r]);
                o[16] = __float2half(acc01[r]);
            }
            {
                int row = row0 + 16 + quad * 4 + r;
                __half* o = hsh + (size_t)row * HID + nbase + l16;
                o[0]  = __float2half(acc10[r]);
                o[16] = __float2half(acc11[r]);
            }
        }
    }
}

// ------- phase C: inline bin prefix + per-bin hist/scan -> rowptr/dis/csr ----
__global__ __launch_bounds__(256) void k_place2(const int* __restrict__ bcnt,
                                                const unsigned int* __restrict__ binned,
                                                int* __restrict__ rowptr,
                                                float* __restrict__ dis,
                                                __half* __restrict__ dish,
                                                int* __restrict__ csr,
                                                int N, int E, int nbin) {
    __shared__ int h[NPB];
    __shared__ int lb[NPB];
    __shared__ int cur[NPB];
    __shared__ int red[256];
    const int b = blockIdx.x;
    const int tid = threadIdx.x;

    int partial = 0;
    for (int i = tid; i < b; i += 256) partial += bcnt[i];
    red[tid] = partial;
    if (tid < NPB) h[tid] = 0;
    __syncthreads();
    #pragma unroll
    for (int off = 128; off > 0; off >>= 1) {
        if (tid < off) red[tid] += red[tid + off];
        __syncthreads();
    }
    const int rb = red[0];

    const int m = min(bcnt[b], BCAP);
    const unsigned int* p = binned + (size_t)b * BCAP;
    for (int i = tid; i < m; i += 256) atomicAdd(&h[p[i] >> 17], 1);
    __syncthreads();
    if (tid < NPB) lb[tid] = h[tid];
    __syncthreads();
    #pragma unroll
    for (int off = 1; off < NPB; off <<= 1) {
        int t = (tid < NPB && tid >= off) ? lb[tid - off] : 0;
        __syncthreads();
        if (tid < NPB) lb[tid] += t;
        __syncthreads();
    }
    if (tid < NPB) {
        int ex = lb[tid] - h[tid];
        int node = b * NPB + tid;
        if (node < N) {
            float dv = rsqrtf(1.0f + (float)h[tid]);
            rowptr[node] = rb + ex;
            dis[node] = dv;
            dish[node] = __float2half(dv);
        }
        lb[tid] = ex;
        cur[tid] = 0;
    }
    if (b == nbin - 1 && tid == 0) rowptr[N] = E;
    __syncthreads();
    for (int i = tid; i < m; i += 256) {
        unsigned v = p[i];
        int dl = v >> 17;
        int r = atomicAdd(&cur[dl], 1);
        csr[rb + lb[dl] + r] = (int)(v & 0x1FFFF);
    }
}

// ------- agg1: pk-fp16 weighted gather + bias/ReLU + GEMM2 (128->10) ---------
// One wave per node, 4 sub-groups of 16 lanes; clamped-prefetch rounds of 16
// edges; per-edge weight dish[src] folded via v_pk_fma_f16 (4 ops / 16B row).
__global__ __launch_bounds__(256) void k_agg1(const __half* __restrict__ hsh,
                                              const int* __restrict__ rowptr,
                                              const int* __restrict__ csr,
                                              const float* __restrict__ dis,
                                              const __half* __restrict__ dish,
                                              const float* __restrict__ b1,
                                              const float* __restrict__ W2,
                                              __half* __restrict__ h2h, int N) {
    __shared__ float sWT[NC][IN_F];              // transposed W2: [c][f]
    for (int i = threadIdx.x; i < NC * IN_F; i += 256)
        sWT[i >> 7][i & 127] = W2[(i & 127) * NC + (i >> 7)];
    __syncthreads();

    const int node = blockIdx.x * 4 + (threadIdx.x >> 6);
    if (node >= N) return;
    const int lane = threadIdx.x & 63;
    const int g   = lane >> 4;
    const int l16 = lane & 15;
    const int f0  = l16 * 8;       // 8 halves per lane

    const int beg = rowptr[node], end = rowptr[node + 1];
    const __half2 hz = __half2half2(__float2half(0.0f));

    __half2 acc2[4] = {hz, hz, hz, hz};
    if (g == 0) {   // self term: dish[node] * hsh[node]
        float4 r = *(const float4*)(hsh + (size_t)node * HID + f0);
        const __half2* hh = (const __half2*)&r;
        __half2 dn2 = __half2half2(dish[node]);
        acc2[0] = __hmul2(dn2, hh[0]);
        acc2[1] = __hmul2(dn2, hh[1]);
        acc2[2] = __hmul2(dn2, hh[2]);
        acc2[3] = __hmul2(dn2, hh[3]);
    }

    const int last = end - 1;
    for (int j0 = beg + g; j0 < end; j0 += 16) {
        int j1 = j0 + 4, j2 = j0 + 8, j3 = j0 + 12;
        int s0 = csr[j0];
        int s1 = csr[min(j1, last)];
        int s2 = csr[min(j2, last)];
        int s3 = csr[min(j3, last)];
        float4 r0 = *(const float4*)(hsh + (size_t)s0 * HID + f0);
        float4 r1 = *(const float4*)(hsh + (size_t)s1 * HID + f0);
        float4 r2 = *(const float4*)(hsh + (size_t)s2 * HID + f0);
        float4 r3 = *(const float4*)(hsh + (size_t)s3 * HID + f0);
        __half2 w0 = __half2half2(dish[s0]);
        __half2 w1 = (j1 < end) ? __half2half2(dish[s1]) : hz;
        __half2 w2 = (j2 < end) ? __half2half2(dish[s2]) : hz;
        __half2 w3 = (j3 < end) ? __half2half2(dish[s3]) : hz;
        const __half2* h0 = (const __half2*)&r0;
        const __half2* h1 = (const __half2*)&r1;
        const __half2* h2 = (const __half2*)&r2;
        const __half2* h3 = (const __half2*)&r3;
        #pragma unroll
        for (int i = 0; i < 4; i++) {
            acc2[i] = __hfma2(w0, h0[i], acc2[i]);
            acc2[i] = __hfma2(w1, h1[i], acc2[i]);
            acc2[i] = __hfma2(w2, h2[i], acc2[i]);
            acc2[i] = __hfma2(w3, h3[i], acc2[i]);
        }
    }

    // merge the 4 sub-groups (fp16 butterflies), then widen
    #pragma unroll
    for (int i = 0; i < 4; i++) {
        acc2[i] = __hadd2(acc2[i], shfl_xor_h2(acc2[i], 16));
        acc2[i] = __hadd2(acc2[i], shfl_xor_h2(acc2[i], 32));
    }
    float acc[8];
    #pragma unroll
    for (int i = 0; i < 4; i++) {
        float2 t = __half22float2(acc2[i]);
        acc[2 * i] = t.x; acc[2 * i + 1] = t.y;
    }

    const float d = dis[node];
    float4 ba = *(const float4*)(b1 + f0);
    float4 bb = *(const float4*)(b1 + f0 + 4);
    float h[8];
    h[0] = fmaxf(fmaf(d, acc[0], ba.x), 0.0f);
    h[1] = fmaxf(fmaf(d, acc[1], ba.y), 0.0f);
    h[2] = fmaxf(fmaf(d, acc[2], ba.z), 0.0f);
    h[3] = fmaxf(fmaf(d, acc[3], ba.w), 0.0f);
    h[4] = fmaxf(fmaf(d, acc[4], bb.x), 0.0f);
    h[5] = fmaxf(fmaf(d, acc[5], bb.y), 0.0f);
    h[6] = fmaxf(fmaf(d, acc[6], bb.z), 0.0f);
    h[7] = fmaxf(fmaf(d, acc[7], bb.w), 0.0f);

    const int cb = (g == 0) ? 0 : (g == 1) ? 3 : (g == 2) ? 6 : 8;
    const int nc = (g < 2) ? 3 : 2;
    float p[3];
    #pragma unroll
    for (int ci = 0; ci < 3; ci++) {
        if (ci < nc) {
            int c = cb + ci;
            float4 wa = *(const float4*)&sWT[c][f0];
            float4 wb = *(const float4*)&sWT[c][f0 + 4];
            float t = fmaf(h[0], wa.x, fmaf(h[1], wa.y, fmaf(h[2], wa.z, h[3] * wa.w)));
            t = fmaf(h[4], wb.x, fmaf(h[5], wb.y, fmaf(h[6], wb.z, fmaf(h[7], wb.w, t))));
            #pragma unroll
            for (int off = 1; off < 16; off <<= 1) t += __shfl_xor(t, off, 64);
            p[ci] = t;
        }
    }
    if (l16 == 0) {
        __half* o = h2h + (size_t)node * H2P + cb;
        for (int ci = 0; ci < nc; ci++) o[ci] = __float2half(d * p[ci]);
    }
}

// ------- agg2: pk-fp16 gather (32B rows, 2 lanes/node) + bias + softmax ------
__global__ __launch_bounds__(256) void k_agg2(const __half* __restrict__ h2h,
                                              const int* __restrict__ rowptr,
                                              const int* __restrict__ csr,
                                              const float* __restrict__ dis,
                                              const float* __restrict__ b2,
                                              float* __restrict__ out, int N) {
    int t = blockIdx.x * 256 + threadIdx.x;
    int node = t >> 1;
    int q = t & 1;
    if (node >= N) return;
    const int base = q * 8;    // halves
    const __half2 hz = __half2half2(__float2half(0.0f));
    const __half2 ho = __half2half2(__float2half(1.0f));

    __half2 a2[4];
    {
        float4 r = *(const float4*)(h2h + (size_t)node * H2P + base);   // self
        const __half2* hh = (const __half2*)&r;
        a2[0] = hh[0]; a2[1] = hh[1]; a2[2] = hh[2]; a2[3] = hh[3];
    }
    const int beg = rowptr[node], end = rowptr[node + 1];
    const int last = end - 1;
    for (int j0 = beg; j0 < end; j0 += 4) {
        int s0 = csr[j0];
        int s1 = csr[min(j0 + 1, last)];
        int s2 = csr[min(j0 + 2, last)];
        int s3 = csr[min(j0 + 3, last)];
        __half2 w1 = (j0 + 1 < end) ? ho : hz;
        __half2 w2 = (j0 + 2 < end) ? ho : hz;
        __half2 w3 = (j0 + 3 < end) ? ho : hz;
        float4 r0 = *(const float4*)(h2h + (size_t)s0 * H2P + base);
        float4 r1 = *(const float4*)(h2h + (size_t)s1 * H2P + base);
        float4 r2 = *(const float4*)(h2h + (size_t)s2 * H2P + base);
        float4 r3 = *(const float4*)(h2h + (size_t)s3 * H2P + base);
        const __half2* h0 = (const __half2*)&r0;
        const __half2* h1 = (const __half2*)&r1;
        const __half2* h2 = (const __half2*)&r2;
        const __half2* h3 = (const __half2*)&r3;
        #pragma unroll
        for (int i = 0; i < 4; i++) {
            a2[i] = __hadd2(a2[i], h0[i]);
            a2[i] = __hfma2(w1, h1[i], a2[i]);
            a2[i] = __hfma2(w2, h2[i], a2[i]);
            a2[i] = __hfma2(w3, h3[i], a2[i]);
        }
    }

    float a[8];
    #pragma unroll
    for (int i = 0; i < 4; i++) {
        float2 tt = __half22float2(a2[i]);
        a[2 * i] = tt.x; a[2 * i + 1] = tt.y;
    }

    const float d = dis[node];
    float vv[8];
    #pragma unroll
    for (int i = 0; i < 8; i++) {
        int f = base + i;
        vv[i] = (f < NC) ? fmaf(d, a[i], b2[f]) : -1e30f;
    }
    float m = vv[0];
    #pragma unroll
    for (int i = 1; i < 8; i++) m = fmaxf(m, vv[i]);
    m = fmaxf(m, __shfl_xor(m, 1, 64));
    float e[8];
    float s = 0.0f;
    #pragma unroll
    for (int i = 0; i < 8; i++) { e[i] = (base + i < NC) ? expf(vv[i] - m) : 0.0f; s += e[i]; }
    s += __shfl_xor(s, 1, 64);
    float inv = 1.0f / s;

    float* o = out + (size_t)node * NC;
    if (q == 0) {
        *(float2*)(o + 0) = make_float2(e[0] * inv, e[1] * inv);
        *(float2*)(o + 2) = make_float2(e[2] * inv, e[3] * inv);
        *(float2*)(o + 4) = make_float2(e[4] * inv, e[5] * inv);
        *(float2*)(o + 6) = make_float2(e[6] * inv, e[7] * inv);
    } else {
        *(float2*)(o + 8) = make_float2(e[0] * inv, e[1] * inv);
    }
}

extern "C" void kernel_launch(void* const* d_in, const int* in_sizes, int n_in,
                              void* d_out, int out_size, void* d_ws, size_t ws_size,
                              hipStream_t stream) {
    const float* x  = (const float*)d_in[0];
    const int*   ei = (const int*)d_in[1];
    const float* W1 = (const float*)d_in[2];
    const float* b1 = (const float*)d_in[3];
    const float* W2 = (const float*)d_in[4];
    const float* b2 = (const float*)d_in[5];
    float* out = (float*)d_out;

    const int N = in_sizes[0] / IN_F;   // 100000
    const int E = in_sizes[1] / 2;      // 1600000
    const int* esrc = ei;
    const int* edst = ei + E;
    const int nbin = (N + NPB - 1) / NPB;       // 782
    const int nbinblk = (E + EPB2 - 1) / EPB2;  // 391

    char* ws = (char*)d_ws;
    int*    rowptr  = (int*)(ws);                           // (N+1)*4
    float*  dis     = (float*)(ws + 0x80000);               // 400 KB
    __half* dish    = (__half*)(ws + 0x100000);             // 200 KB
    int*    bcnt    = (int*)(ws + 0x140000);                // 3.1 KB
    unsigned int* binned = (unsigned int*)(ws + 0x150000);  // 8.03 MB
    int*    csr     = (int*)(ws + 0x960000);                // 6.4 MB
    __half* hsh     = (__half*)(ws + 0x1000000);            // 25.6 MB
    __half* h2h     = (__half*)(ws + 0x2A00000);            // 3.2 MB

    hipMemsetAsync(bcnt, 0, (size_t)nbin * sizeof(int), stream);

    k_bingemm<<<nbinblk + N / 32, 256, 0, stream>>>(esrc, edst, bcnt, binned,
                                                    x, W1, hsh, E, nbin, nbinblk);
    k_place2 <<<nbin, 256, 0, stream>>>(bcnt, binned, rowptr, dis, dish, csr, N, E, nbin);
    k_agg1   <<<(N + 3) / 4, 256, 0, stream>>>(hsh, rowptr, csr, dis, dish, b1, W2, h2h, N);
    k_agg2   <<<(int)(((size_t)N * 2 + 255) / 256), 256, 0, stream>>>(h2h, rowptr, csr, dis, b2, out, N);
}

// Round 10
// 250.772 us; speedup vs baseline: 1.0149x; 1.0149x over previous
//
#include <hip/hip_runtime.h>
#include <hip/hip_fp16.h>

#define IN_F 128
#define HID  128
#define NC   10
#define H2P  16     // h2 row stride in HALVES (32 B)
#define NPB  128    // nodes per bin (bin = dst>>7, local = dst&127)
#define NBMAX 784   // max bins (N=100000 -> 782)
#define BCAP 2560   // per-bin edge capacity (mean 2046, +11 sigma)
#define EPB  4096   // edges per k_bin block (1024 thr x 4) -> 391 blocks

typedef _Float16 f16x8 __attribute__((ext_vector_type(8)));
typedef float f32x4 __attribute__((ext_vector_type(4)));
typedef int int4a __attribute__((ext_vector_type(4), aligned(4)));  // 4B-aligned vec4

__device__ inline __half2 shfl_xor_h2(__half2 v, int mask) {
    int i = __shfl_xor(*reinterpret_cast<int*>(&v), mask, 64);
    return *reinterpret_cast<__half2*>(&i);
}

// ------- phase A: bin edges by dst>>7, packed (dl<<17)|src; blk0 preps WT ----
__global__ __launch_bounds__(1024) void k_bin(const int* __restrict__ src,
                                              const int* __restrict__ dst,
                                              int* __restrict__ bcnt,
                                              unsigned int* __restrict__ binned,
                                              const float* __restrict__ W1,
                                              __half* __restrict__ WT,
                                              int E, int nbin) {
    __shared__ int hist[NBMAX];
    __shared__ int base[NBMAX];
    __shared__ int lcur[NBMAX];
    const int tid = threadIdx.x;

    if (blockIdx.x == 0) {   // WT[n][k] = fp16(W1[k][n]); consumed 2 launches later
        for (int i = tid; i < IN_F * HID; i += 1024) {
            int k = i >> 7, n = i & 127;
            WT[n * IN_F + k] = __float2half(W1[k * HID + n]);
        }
    }

    for (int b = tid; b < nbin; b += 1024) { hist[b] = 0; lcur[b] = 0; }
    __syncthreads();

    const int e0 = blockIdx.x * EPB + tid;
    int d[4];
    #pragma unroll
    for (int u = 0; u < 4; u++) {
        int e = e0 + u * 1024;
        d[u] = (e < E) ? dst[e] : -1;
        if (d[u] >= 0) atomicAdd(&hist[d[u] >> 7], 1);
    }
    __syncthreads();
    for (int b = tid; b < nbin; b += 1024) {
        int h = hist[b];
        base[b] = h ? atomicAdd(&bcnt[b], h) : 0;
    }
    __syncthreads();
    #pragma unroll
    for (int u = 0; u < 4; u++) {
        int e = e0 + u * 1024;
        if (e < E) {
            int dd = d[u];
            int b = dd >> 7;
            int s = src[e];
            int o = base[b] + atomicAdd(&lcur[b], 1);
            if (o < BCAP)
                binned[(size_t)b * BCAP + o] = ((unsigned)(dd & 127) << 17) | (unsigned)s;
        }
    }
}

// ------- phase C: inline bin prefix + per-bin hist/scan -> rowptr/dis/csr ----
__global__ __launch_bounds__(256) void k_place2(const int* __restrict__ bcnt,
                                                const unsigned int* __restrict__ binned,
                                                int* __restrict__ rowptr,
                                                float* __restrict__ dis,
                                                int* __restrict__ csr,
                                                int N, int E, int nbin) {
    __shared__ int h[NPB];
    __shared__ int lb[NPB];
    __shared__ int cur[NPB];
    __shared__ int red[256];
    const int b = blockIdx.x;
    const int tid = threadIdx.x;

    int partial = 0;
    for (int i = tid; i < b; i += 256) partial += bcnt[i];
    red[tid] = partial;
    if (tid < NPB) h[tid] = 0;
    __syncthreads();
    #pragma unroll
    for (int off = 128; off > 0; off >>= 1) {
        if (tid < off) red[tid] += red[tid + off];
        __syncthreads();
    }
    const int rb = red[0];

    const int m = min(bcnt[b], BCAP);
    const unsigned int* p = binned + (size_t)b * BCAP;
    for (int i = tid; i < m; i += 256) atomicAdd(&h[p[i] >> 17], 1);
    __syncthreads();
    if (tid < NPB) lb[tid] = h[tid];
    __syncthreads();
    #pragma unroll
    for (int off = 1; off < NPB; off <<= 1) {
        int t = (tid < NPB && tid >= off) ? lb[tid - off] : 0;
        __syncthreads();
        if (tid < NPB) lb[tid] += t;
        __syncthreads();
    }
    if (tid < NPB) {
        int ex = lb[tid] - h[tid];
        int node = b * NPB + tid;
        if (node < N) {
            rowptr[node] = rb + ex;
            dis[node] = rsqrtf(1.0f + (float)h[tid]);
        }
        lb[tid] = ex;
        cur[tid] = 0;
    }
    if (b == nbin - 1 && tid == 0) rowptr[N] = E;
    __syncthreads();
    for (int i = tid; i < m; i += 256) {
        unsigned v = p[i];
        int dl = v >> 17;
        int r = atomicAdd(&cur[dl], 1);
        csr[rb + lb[dl] + r] = (int)(v & 0x1FFFF);
    }
}

// ---------------- GEMM1 (MFMA fp16): hsh = fp16(dis[row] * (X @ W1)) ---------
__global__ __launch_bounds__(256) void k_gemm1(const float* __restrict__ X,
                                               const __half* __restrict__ WT,
                                               const float* __restrict__ dis,
                                               __half* __restrict__ outh) {
    __shared__ _Float16 sX[32 * IN_F];
    __shared__ _Float16 sW[128 * IN_F];
    const int tid = threadIdx.x;
    const int row0 = blockIdx.x * 32;

    {
        int n = tid >> 1, part = tid & 1;
        const f16x8* src = (const f16x8*)(WT + n * IN_F + part * 64);
        f16x8* dst = (f16x8*)(sW + n * IN_F + part * 64);
        #pragma unroll
        for (int c = 0; c < 8; c++) dst[c] = src[c];
    }
    {
        int r = tid >> 3;
        int k0 = (tid & 7) * 16;
        const float* sp = X + (size_t)(row0 + r) * IN_F + k0;
        float4 f0 = *(const float4*)(sp);
        float4 f1 = *(const float4*)(sp + 4);
        float4 f2 = *(const float4*)(sp + 8);
        float4 f3 = *(const float4*)(sp + 12);
        f16x8 h0, h1;
        h0[0] = (_Float16)f0.x; h0[1] = (_Float16)f0.y;
        h0[2] = (_Float16)f0.z; h0[3] = (_Float16)f0.w;
        h0[4] = (_Float16)f1.x; h0[5] = (_Float16)f1.y;
        h0[6] = (_Float16)f1.z; h0[7] = (_Float16)f1.w;
        h1[0] = (_Float16)f2.x; h1[1] = (_Float16)f2.y;
        h1[2] = (_Float16)f2.z; h1[3] = (_Float16)f2.w;
        h1[4] = (_Float16)f3.x; h1[5] = (_Float16)f3.y;
        h1[6] = (_Float16)f3.z; h1[7] = (_Float16)f3.w;
        *(f16x8*)(sX + r * IN_F + k0) = h0;
        *(f16x8*)(sX + r * IN_F + k0 + 8) = h1;
    }
    __syncthreads();

    const int wave = tid >> 6;
    const int lane = tid & 63;
    const int quad = lane >> 4;
    const int l16 = lane & 15;
    const int nbase = wave * 32;

    f32x4 acc00 = {0,0,0,0}, acc01 = {0,0,0,0}, acc10 = {0,0,0,0}, acc11 = {0,0,0,0};

    #pragma unroll
    for (int kc = 0; kc < 4; kc++) {
        const int koff = kc * 32 + quad * 8;
        f16x8 a0 = *(const f16x8*)(sX + l16 * IN_F + koff);
        f16x8 a1 = *(const f16x8*)(sX + (16 + l16) * IN_F + koff);
        f16x8 b0 = *(const f16x8*)(sW + (nbase + l16) * IN_F + koff);
        f16x8 b1 = *(const f16x8*)(sW + (nbase + 16 + l16) * IN_F + koff);
        acc00 = __builtin_amdgcn_mfma_f32_16x16x32_f16(a0, b0, acc00, 0, 0, 0);
        acc01 = __builtin_amdgcn_mfma_f32_16x16x32_f16(a0, b1, acc01, 0, 0, 0);
        acc10 = __builtin_amdgcn_mfma_f32_16x16x32_f16(a1, b0, acc10, 0, 0, 0);
        acc11 = __builtin_amdgcn_mfma_f32_16x16x32_f16(a1, b1, acc11, 0, 0, 0);
    }

    #pragma unroll
    for (int r = 0; r < 4; r++) {
        {
            int row = row0 + quad * 4 + r;
            float d = dis[row];
            __half* o = outh + (size_t)row * HID + nbase + l16;
            o[0]  = __float2half(acc00[r] * d);
            o[16] = __float2half(acc01[r] * d);
        }
        {
            int row = row0 + 16 + quad * 4 + r;
            float d = dis[row];
            __half* o = outh + (size_t)row * HID + nbase + l16;
            o[0]  = __float2half(acc10[r] * d);
            o[16] = __float2half(acc11[r] * d);
        }
    }
}

// ------- agg1: pk-fp16 gather (pre-scaled rows) + bias/ReLU + GEMM2 ----------
// One wave per node, 4 sub-groups of 16 lanes. Sub-group g owns contiguous
// 4-edge spans [beg+4g+16t, +4). Per round: ONE csr dwordx4 (clamped to E-4,
// tail handled by offset mask) + 4 row dwordx4 loads; accumulate = __hfma2
// with 0/1 mask. 5 vmem + ~35 VALU per 4 edges.
__global__ __launch_bounds__(256) void k_agg1(const __half* __restrict__ hsh,
                                              const int* __restrict__ rowptr,
                                              const int* __restrict__ csr,
                                              const float* __restrict__ dis,
                                              const float* __restrict__ b1,
                                              const float* __restrict__ W2,
                                              __half* __restrict__ h2h,
                                              int N, int E) {
    __shared__ float sWT[NC][IN_F];              // transposed W2: [c][f]
    for (int i = threadIdx.x; i < NC * IN_F; i += 256)
        sWT[i >> 7][i & 127] = W2[(i & 127) * NC + (i >> 7)];
    __syncthreads();

    const int node = blockIdx.x * 4 + (threadIdx.x >> 6);
    if (node >= N) return;
    const int lane = threadIdx.x & 63;
    const int g   = lane >> 4;
    const int l16 = lane & 15;
    const int f0  = l16 * 8;       // 8 halves per lane

    const int beg = rowptr[node], end = rowptr[node + 1];
    const __half2 hz = __half2half2(__float2half(0.0f));
    const __half2 ho = __half2half2(__float2half(1.0f));
    const unsigned nclamp = (unsigned)(N - 1);

    __half2 acc2[4] = {hz, hz, hz, hz};
    if (g == 0) {   // self term (hsh pre-scaled by dis[src])
        float4 r = *(const float4*)(hsh + (size_t)node * HID + f0);
        const __half2* hh = (const __half2*)&r;
        acc2[0] = hh[0]; acc2[1] = hh[1]; acc2[2] = hh[2]; acc2[3] = hh[3];
    }

    for (int j0 = beg + 4 * g; j0 < end; j0 += 16) {
        int bj = min(j0, E - 4);
        int off = j0 - bj;                 // 0 except at the very array tail
        int rem = end - j0;                // >= 1
        int4a cv = *(const int4a*)(csr + bj);
        unsigned s0 = min((unsigned)cv[0], nclamp);
        unsigned s1 = min((unsigned)cv[1], nclamp);
        unsigned s2 = min((unsigned)cv[2], nclamp);
        unsigned s3 = min((unsigned)cv[3], nclamp);
        __half2 w0 = ((unsigned)(0 - off) < (unsigned)rem) ? ho : hz;
        __half2 w1 = ((unsigned)(1 - off) < (unsigned)rem) ? ho : hz;
        __half2 w2 = ((unsigned)(2 - off) < (unsigned)rem) ? ho : hz;
        __half2 w3 = ((unsigned)(3 - off) < (unsigned)rem) ? ho : hz;
        float4 r0 = *(const float4*)(hsh + (size_t)s0 * HID + f0);
        float4 r1 = *(const float4*)(hsh + (size_t)s1 * HID + f0);
        float4 r2 = *(const float4*)(hsh + (size_t)s2 * HID + f0);
        float4 r3 = *(const float4*)(hsh + (size_t)s3 * HID + f0);
        const __half2* h0 = (const __half2*)&r0;
        const __half2* h1 = (const __half2*)&r1;
        const __half2* h2 = (const __half2*)&r2;
        const __half2* h3 = (const __half2*)&r3;
        #pragma unroll
        for (int i = 0; i < 4; i++) {
            acc2[i] = __hfma2(w0, h0[i], acc2[i]);
            acc2[i] = __hfma2(w1, h1[i], acc2[i]);
            acc2[i] = __hfma2(w2, h2[i], acc2[i]);
            acc2[i] = __hfma2(w3, h3[i], acc2[i]);
        }
    }

    // merge the 4 sub-groups, then widen
    #pragma unroll
    for (int i = 0; i < 4; i++) {
        acc2[i] = __hadd2(acc2[i], shfl_xor_h2(acc2[i], 16));
        acc2[i] = __hadd2(acc2[i], shfl_xor_h2(acc2[i], 32));
    }
    float acc[8];
    #pragma unroll
    for (int i = 0; i < 4; i++) {
        float2 t = __half22float2(acc2[i]);
        acc[2 * i] = t.x; acc[2 * i + 1] = t.y;
    }

    const float d = dis[node];
    float4 ba = *(const float4*)(b1 + f0);
    float4 bb = *(const float4*)(b1 + f0 + 4);
    float h[8];
    h[0] = fmaxf(fmaf(d, acc[0], ba.x), 0.0f);
    h[1] = fmaxf(fmaf(d, acc[1], ba.y), 0.0f);
    h[2] = fmaxf(fmaf(d, acc[2], ba.z), 0.0f);
    h[3] = fmaxf(fmaf(d, acc[3], ba.w), 0.0f);
    h[4] = fmaxf(fmaf(d, acc[4], bb.x), 0.0f);
    h[5] = fmaxf(fmaf(d, acc[5], bb.y), 0.0f);
    h[6] = fmaxf(fmaf(d, acc[6], bb.z), 0.0f);
    h[7] = fmaxf(fmaf(d, acc[7], bb.w), 0.0f);

    const int cb = (g == 0) ? 0 : (g == 1) ? 3 : (g == 2) ? 6 : 8;
    const int nc = (g < 2) ? 3 : 2;
    float p[3];
    #pragma unroll
    for (int ci = 0; ci < 3; ci++) {
        if (ci < nc) {
            int c = cb + ci;
            float4 wa = *(const float4*)&sWT[c][f0];
            float4 wb = *(const float4*)&sWT[c][f0 + 4];
            float t = fmaf(h[0], wa.x, fmaf(h[1], wa.y, fmaf(h[2], wa.z, h[3] * wa.w)));
            t = fmaf(h[4], wb.x, fmaf(h[5], wb.y, fmaf(h[6], wb.z, fmaf(h[7], wb.w, t))));
            #pragma unroll
            for (int off = 1; off < 16; off <<= 1) t += __shfl_xor(t, off, 64);
            p[ci] = t;
        }
    }
    if (l16 == 0) {
        __half* o = h2h + (size_t)node * H2P + cb;
        for (int ci = 0; ci < nc; ci++) o[ci] = __float2half(d * p[ci]);
    }
}

// ------- agg2: pk-fp16 gather (32B rows, 2 lanes/node) + bias + softmax ------
// Rounds of 4 edges via one clamped csr dwordx4 + 4 row float4 loads.
__global__ __launch_bounds__(256) void k_agg2(const __half* __restrict__ h2h,
                                              const int* __restrict__ rowptr,
                                              const int* __restrict__ csr,
                                              const float* __restrict__ dis,
                                              const float* __restrict__ b2,
                                              float* __restrict__ out,
                                              int N, int E) {
    int t = blockIdx.x * 256 + threadIdx.x;
    int node = t >> 1;
    int q = t & 1;
    if (node >= N) return;
    const int base = q * 8;    // halves
    const __half2 hz = __half2half2(__float2half(0.0f));
    const __half2 ho = __half2half2(__float2half(1.0f));
    const unsigned nclamp = (unsigned)(N - 1);

    __half2 a2[4];
    {
        float4 r = *(const float4*)(h2h + (size_t)node * H2P + base);   // self
        const __half2* hh = (const __half2*)&r;
        a2[0] = hh[0]; a2[1] = hh[1]; a2[2] = hh[2]; a2[3] = hh[3];
    }
    const int beg = rowptr[node], end = rowptr[node + 1];
    for (int j0 = beg; j0 < end; j0 += 4) {
        int bj = min(j0, E - 4);
        int off = j0 - bj;
        int rem = end - j0;
        int4a cv = *(const int4a*)(csr + bj);
        unsigned s0 = min((unsigned)cv[0], nclamp);
        unsigned s1 = min((unsigned)cv[1], nclamp);
        unsigned s2 = min((unsigned)cv[2], nclamp);
        unsigned s3 = min((unsigned)cv[3], nclamp);
        __half2 w0 = ((unsigned)(0 - off) < (unsigned)rem) ? ho : hz;
        __half2 w1 = ((unsigned)(1 - off) < (unsigned)rem) ? ho : hz;
        __half2 w2 = ((unsigned)(2 - off) < (unsigned)rem) ? ho : hz;
        __half2 w3 = ((unsigned)(3 - off) < (unsigned)rem) ? ho : hz;
        float4 r0 = *(const float4*)(h2h + (size_t)s0 * H2P + base);
        float4 r1 = *(const float4*)(h2h + (size_t)s1 * H2P + base);
        float4 r2 = *(const float4*)(h2h + (size_t)s2 * H2P + base);
        float4 r3 = *(const float4*)(h2h + (size_t)s3 * H2P + base);
        const __half2* h0 = (const __half2*)&r0;
        const __half2* h1 = (const __half2*)&r1;
        const __half2* h2 = (const __half2*)&r2;
        const __half2* h3 = (const __half2*)&r3;
        #pragma unroll
        for (int i = 0; i < 4; i++) {
            a2[i] = __hfma2(w0, h0[i], a2[i]);
            a2[i] = __hfma2(w1, h1[i], a2[i]);
            a2[i] = __hfma2(w2, h2[i], a2[i]);
            a2[i] = __hfma2(w3, h3[i], a2[i]);
        }
    }

    float a[8];
    #pragma unroll
    for (int i = 0; i < 4; i++) {
        float2 tt = __half22float2(a2[i]);
        a[2 * i] = tt.x; a[2 * i + 1] = tt.y;
    }

    const float d = dis[node];
    float vv[8];
    #pragma unroll
    for (int i = 0; i < 8; i++) {
        int f = base + i;
        vv[i] = (f < NC) ? fmaf(d, a[i], b2[f]) : -1e30f;
    }
    float m = vv[0];
    #pragma unroll
    for (int i = 1; i < 8; i++) m = fmaxf(m, vv[i]);
    m = fmaxf(m, __shfl_xor(m, 1, 64));
    float e[8];
    float s = 0.0f;
    #pragma unroll
    for (int i = 0; i < 8; i++) { e[i] = (base + i < NC) ? expf(vv[i] - m) : 0.0f; s += e[i]; }
    s += __shfl_xor(s, 1, 64);
    float inv = 1.0f / s;

    float* o = out + (size_t)node * NC;
    if (q == 0) {
        *(float2*)(o + 0) = make_float2(e[0] * inv, e[1] * inv);
        *(float2*)(o + 2) = make_float2(e[2] * inv, e[3] * inv);
        *(float2*)(o + 4) = make_float2(e[4] * inv, e[5] * inv);
        *(float2*)(o + 6) = make_float2(e[6] * inv, e[7] * inv);
    } else {
        *(float2*)(o + 8) = make_float2(e[0] * inv, e[1] * inv);
    }
}

extern "C" void kernel_launch(void* const* d_in, const int* in_sizes, int n_in,
                              void* d_out, int out_size, void* d_ws, size_t ws_size,
                              hipStream_t stream) {
    const float* x  = (const float*)d_in[0];
    const int*   ei = (const int*)d_in[1];
    const float* W1 = (const float*)d_in[2];
    const float* b1 = (const float*)d_in[3];
    const float* W2 = (const float*)d_in[4];
    const float* b2 = (const float*)d_in[5];
    float* out = (float*)d_out;

    const int N = in_sizes[0] / IN_F;   // 100000
    const int E = in_sizes[1] / 2;      // 1600000
    const int* esrc = ei;
    const int* edst = ei + E;
    const int nbin = (N + NPB - 1) / NPB;  // 782

    char* ws = (char*)d_ws;
    int*    rowptr  = (int*)(ws);                           // (N+1)*4
    float*  dis     = (float*)(ws + 0x80000);               // 400 KB
    int*    bcnt    = (int*)(ws + 0x100000);                // 3.1 KB
    __half* WT      = (__half*)(ws + 0x110000);             // 32 KB
    unsigned int* binned = (unsigned int*)(ws + 0x140000);  // 8.0 MB
    int*    csr     = (int*)(ws + 0x940000);                // 6.4 MB
    __half* hsh     = (__half*)(ws + 0x1040000);            // 25.6 MB
    __half* h2h     = (__half*)(ws + 0x2A00000);            // 3.2 MB

    hipMemsetAsync(bcnt, 0, (size_t)nbin * sizeof(int), stream);

    k_bin   <<<(E + EPB - 1) / EPB, 1024, 0, stream>>>(esrc, edst, bcnt, binned, W1, WT, E, nbin);
    k_place2<<<nbin, 256, 0, stream>>>(bcnt, binned, rowptr, dis, csr, N, E, nbin);
    k_gemm1 <<<N / 32, 256, 0, stream>>>(x, WT, dis, hsh);
    k_agg1  <<<(N + 3) / 4, 256, 0, stream>>>(hsh, rowptr, csr, dis, b1, W2, h2h, N, E);
    k_agg2  <<<(int)(((size_t)N * 2 + 255) / 256), 256, 0, stream>>>(h2h, rowptr, csr, dis, b2, out, N, E);
}